// Round 5
// baseline (732.242 us; speedup 1.0000x reference)
//
#include <hip/hip_runtime.h>
#include <hip/hip_bf16.h>

#define K_CODES 8192
#define DIM     512
#define N_VEC   32768
#define MARGIN  0.5f   // flag threshold on g = x.e - e2/2 ; ~10 sigma of bf16 err

typedef __attribute__((ext_vector_type(8))) short   short8;   // bf16x8 MFMA operand
typedef __attribute__((ext_vector_type(8))) unsigned short ushort8;
typedef __attribute__((ext_vector_type(4))) float   float4x;  // MFMA C/D frag

// async global->LDS, 16 B/lane. LDS dest = wave-uniform base + lane*16.
__device__ inline void gl_lds16(const void* g, void* l) {
    __builtin_amdgcn_global_load_lds(
        (const __attribute__((address_space(1))) unsigned int*)g,
        (__attribute__((address_space(3))) unsigned int*)l, 16, 0, 0);
}

// fp32 -> bf16 bits, round-to-nearest-even
__device__ inline unsigned short f2bf(float f) {
    unsigned int u = __float_as_uint(f);
    return (unsigned short)((u + 0x7FFFu + ((u >> 16) & 1u)) >> 16);
}

// ---------------------------------------------------------------------------
// Kernel 1: prep. rows [0,N_VEC) from z -> zh + x2 ; rows [N_VEC,+K) from cb
// -> ch + hne2 = -0.5*||e||^2.  One wave per row.
// ---------------------------------------------------------------------------
__global__ __launch_bounds__(256) void vq_prep(
    const float* __restrict__ z, const float* __restrict__ cb,
    float* __restrict__ x2, float* __restrict__ hne2,
    unsigned short* __restrict__ zh, unsigned short* __restrict__ ch) {
    int wave = threadIdx.x >> 6;
    int lane = threadIdx.x & 63;
    int row  = blockIdx.x * 4 + wave;
    bool isZ = row < N_VEC;
    int lr = isZ ? row : row - N_VEC;
    const float* src = isZ ? z + (size_t)row * DIM : cb + (size_t)lr * DIM;

    const float4* s4 = (const float4*)src;
    float4 v0 = s4[lane * 2];
    float4 v1 = s4[lane * 2 + 1];
    float f[8] = {v0.x, v0.y, v0.z, v0.w, v1.x, v1.y, v1.z, v1.w};

    float s = 0.0f;
    ushort8 h8;
#pragma unroll
    for (int i = 0; i < 8; ++i) { s += f[i] * f[i]; h8[i] = f2bf(f[i]); }
    ((ushort8*)(isZ ? zh : ch))[(size_t)lr * 64 + lane] = h8;

#pragma unroll
    for (int off = 32; off >= 1; off >>= 1) s += __shfl_xor(s, off, 64);
    if (lane == 0) {
        if (isZ) x2[lr] = s;
        else     hne2[lr] = -0.5f * s;
    }
}

// ---------------------------------------------------------------------------
// Kernel 2: bf16 MFMA GEMM + fused top-2 argmax of g = x.e - e2/2 + per-tile
// row max (pT) for the rescue candidate filter.
// Block = 128 rows x 4096 codes (half=blockIdx.y), 16 tiles of 256 codes.
// 4 waves in 2x2 (wM x wN); per-wave 64x128 tile = 4 M-frags x 8 N-frags.
// Partials written RACE-FREE to slot = half*2 + wN (4 slots per row).
// pT[tIdx][row], tIdx = slot*16+ct, covers the 128 codes of that wave-tile.
// ---------------------------------------------------------------------------
__global__ __launch_bounds__(256, 2) void vq_gemm(
    const unsigned short* __restrict__ zh, const unsigned short* __restrict__ ch,
    const float* __restrict__ hne2,
    float* __restrict__ pG, int* __restrict__ pN, float* __restrict__ pG2,
    float* __restrict__ pT) {
    __shared__ short8 AsC[1024];   // 128 rows x 8 octet-cells, XOR-swizzled (16 KB)
    __shared__ short8 BsC[2048];   // 256 codes x 8 octet-cells, XOR-swizzled (32 KB)

    const int tid  = threadIdx.x;
    const int w    = tid >> 6;
    const int lane = tid & 63;
    const int wM   = w & 1;
    const int wN   = w >> 1;
    const int rowBase   = blockIdx.x * 128;
    const int half      = blockIdx.y;
    const int codeBase0 = half * 4096;

    const int low3 = lane & 7, m15 = lane & 15, hi4 = lane >> 4;

    unsigned aOff[4];
#pragma unroll
    for (int i = 0; i < 4; ++i) {
        int cell = (w * 4 + i) * 64 + lane;
        int r = cell >> 3, qs = cell & 7, q = qs ^ (r & 7);
        aOff[i] = ((unsigned)(rowBase + r) * DIM + q * 8) * 2;
    }
    unsigned bOff[8];
#pragma unroll
    for (int i = 0; i < 8; ++i) {
        int cell = (w * 8 + i) * 64 + lane;
        int c = cell >> 3, qs = cell & 7, q = qs ^ (c & 7);
        bOff[i] = ((unsigned)c * DIM + q * 8) * 2;   // relative to code-tile base
    }

    int rIdx[4], cIdx[8];
#pragma unroll
    for (int mf = 0; mf < 4; ++mf) rIdx[mf] = (wM * 64 + mf * 16 + m15) * 8;
#pragma unroll
    for (int nf = 0; nf < 8; ++nf) cIdx[nf] = (wN * 128 + nf * 16 + m15) * 8;

    float g1[4][4], g2[4][4];
    int   n1[4][4];
#pragma unroll
    for (int mf = 0; mf < 4; ++mf)
#pragma unroll
        for (int rg = 0; rg < 4; ++rg) {
            g1[mf][rg] = -3.4e38f; g2[mf][rg] = -3.4e38f; n1[mf][rg] = 0;
        }

    const char* pA = (const char*)zh;
    for (int ct = 0; ct < 16; ++ct) {
        const int codeBase = codeBase0 + ct * 256;
        const char* pB = (const char*)ch + (size_t)codeBase * (DIM * 2);
        float4x acc[4][8];
#pragma unroll
        for (int mf = 0; mf < 4; ++mf)
#pragma unroll
            for (int nf = 0; nf < 8; ++nf) acc[mf][nf] = (float4x){0.f, 0.f, 0.f, 0.f};

        for (int dc = 0; dc < DIM; dc += 64) {
            const int dc2 = dc * 2;
            __syncthreads();
#pragma unroll
            for (int i = 0; i < 4; ++i)
                gl_lds16(pA + aOff[i] + dc2, &AsC[(w * 4 + i) * 64]);
#pragma unroll
            for (int i = 0; i < 8; ++i)
                gl_lds16(pB + bOff[i] + dc2, &BsC[(w * 8 + i) * 64]);
            __syncthreads();

#pragma unroll
            for (int ks = 0; ks < 2; ++ks) {
                const int qx = (ks * 4 + hi4) ^ low3;
                short8 a[4];
#pragma unroll
                for (int mf = 0; mf < 4; ++mf) a[mf] = AsC[rIdx[mf] + qx];
#pragma unroll
                for (int nf = 0; nf < 8; ++nf) {
                    short8 b = BsC[cIdx[nf] + qx];
#pragma unroll
                    for (int mf = 0; mf < 4; ++mf)
                        acc[mf][nf] = __builtin_amdgcn_mfma_f32_16x16x32_bf16(
                            a[mf], b, acc[mf][nf], 0, 0, 0);
                }
            }
        }

        // epilogue: running top-2 of g + per-tile row max for rescue filter
        float tm[4][4];
#pragma unroll
        for (int mf = 0; mf < 4; ++mf)
#pragma unroll
            for (int rg = 0; rg < 4; ++rg) tm[mf][rg] = -3.4e38f;
#pragma unroll
        for (int nf = 0; nf < 8; ++nf) {
            int nb = codeBase + wN * 128 + nf * 16 + m15;
            float hv = hne2[nb];
#pragma unroll
            for (int mf = 0; mf < 4; ++mf) {
#pragma unroll
                for (int rg = 0; rg < 4; ++rg) {
                    float g = acc[mf][nf][rg] + hv;
                    tm[mf][rg] = fmaxf(tm[mf][rg], g);
                    if (g > g1[mf][rg]) {
                        g2[mf][rg] = g1[mf][rg];
                        g1[mf][rg] = g; n1[mf][rg] = nb;
                    } else {
                        g2[mf][rg] = fmaxf(g2[mf][rg], g);
                    }
                }
            }
        }
        // cross-lane max within the 16-lane row groups, then one lane writes
#pragma unroll
        for (int off = 1; off <= 8; off <<= 1)
#pragma unroll
            for (int mf = 0; mf < 4; ++mf)
#pragma unroll
                for (int rg = 0; rg < 4; ++rg)
                    tm[mf][rg] = fmaxf(tm[mf][rg], __shfl_xor(tm[mf][rg], off, 64));
        if (m15 == 0) {
            const int tIdx = (half * 2 + wN) * 16 + ct;
#pragma unroll
            for (int mf = 0; mf < 4; ++mf)
#pragma unroll
                for (int rg = 0; rg < 4; ++rg)
                    pT[(size_t)tIdx * N_VEC + rowBase + wM * 64 + mf * 16 + hi4 * 4 + rg]
                        = tm[mf][rg];
        }
    }

    // cross-lane top-2 merge over the 16 lanes sharing each row
#pragma unroll
    for (int mf = 0; mf < 4; ++mf)
#pragma unroll
        for (int rg = 0; rg < 4; ++rg) {
            float a1 = g1[mf][rg], a2 = g2[mf][rg];
            int   an = n1[mf][rg];
#pragma unroll
            for (int off = 1; off <= 8; off <<= 1) {
                float b1 = __shfl_xor(a1, off, 64);
                int   bn = __shfl_xor(an, off, 64);
                float b2 = __shfl_xor(a2, off, 64);
                if (b1 > a1 || (b1 == a1 && bn < an)) {
                    a2 = fmaxf(a1, b2); a1 = b1; an = bn;
                } else {
                    a2 = fmaxf(a2, b1);
                }
            }
            if (m15 == 0) {
                int row  = rowBase + wM * 64 + mf * 16 + hi4 * 4 + rg;
                int slot = half * 2 + wN;          // unique per (block.y, wave-col)
                pG [slot * N_VEC + row] = a1;
                pN [slot * N_VEC + row] = an;
                pG2[slot * N_VEC + row] = a2;
            }
        }
}

// ---------------------------------------------------------------------------
// Kernel 3: merge 4 partial slots per row, flag near-ties, and emit rescue
// candidate entries (row | tile<<16) for tiles whose bf16 max is within
// MARGIN of the row's best. True argmin's tile always qualifies (proof in
// header comment of kernel 4).
// ---------------------------------------------------------------------------
__global__ __launch_bounds__(256) void vq_scan(
    float* __restrict__ pG, const int* __restrict__ pN,
    const float* __restrict__ pG2, const float* __restrict__ pT,
    int* __restrict__ provIdx, int* __restrict__ flags,
    unsigned long long* __restrict__ keys,
    int* __restrict__ pool, int* __restrict__ poolCnt) {
    int r = blockIdx.x * 256 + threadIdx.x;
    float g1 = pG[r], g2 = pG2[r];
    int   n1 = pN[r];
#pragma unroll
    for (int s = 1; s < 4; ++s) {
        float a1 = pG [s * N_VEC + r];
        int   an = pN [s * N_VEC + r];
        float a2 = pG2[s * N_VEC + r];
        if (a1 > g1 || (a1 == g1 && an < n1)) {
            g2 = fmaxf(g1, a2); g1 = a1; n1 = an;
        } else {
            g2 = fmaxf(g2, a1);
        }
    }
    provIdx[r] = n1;
    pG[r] = g1;                       // merged best (for loss)
    int fl = (g1 - g2 < MARGIN) ? 1 : 0;
    flags[r] = fl;
    if (fl) {
        keys[r] = ~0ull;
        float thr = g1 - MARGIN;
        for (int t = 0; t < 64; ++t) {
            if (pT[(size_t)t * N_VEC + r] >= thr) {
                int p = atomicAdd(poolCnt, 1);
                pool[p] = r | (t << 16);
            }
        }
    }
}

// ---------------------------------------------------------------------------
// Kernel 4: exact fp32 rescue over candidate (row, 128-code-tile) entries.
// Safety: the exact argmin c* satisfies g_bf16(c*) >= g_true(c*) - E >=
// g1 - 2E = g1 - MARGIN, so its tile's bf16 max qualifies and c* is scored
// exactly here. One wave per entry: z row broadcast via LDS, 2 rounds of
// 64 codes, packed (kv|code) shuffle-min, one atomicMin per entry.
// kv = e2/2 - x.e > 0 for this data, so fp32-bit ordering == float ordering.
// ---------------------------------------------------------------------------
__global__ __launch_bounds__(256) void vq_rescue(
    const float* __restrict__ z, const float* __restrict__ cb,
    const float* __restrict__ hne2,
    const int* __restrict__ pool, const int* __restrict__ poolCnt,
    unsigned long long* __restrict__ keys) {
    __shared__ float zs[4][512];
    const int tid  = threadIdx.x;
    const int w    = tid >> 6;
    const int lane = tid & 63;
    const int cnt  = *poolCnt;
    const int totalWaves = gridDim.x * 4;
    const int gw   = blockIdx.x * 4 + w;
    const int nIter = (cnt + totalWaves - 1) / totalWaves;

    for (int it = 0; it < nIter; ++it) {
        int ei = it * totalWaves + gw;
        bool active = ei < cnt;
        int e    = pool[active ? ei : 0];
        int row  = e & 0xFFFF;
        int tIdx = e >> 16;
        int half = tIdx >> 5, wN = (tIdx >> 4) & 1, ct = tIdx & 15;
        int base = half * 4096 + ct * 256 + wN * 128;

        __syncthreads();   // uniform trip count across all 4 waves
        const float4* zr = (const float4*)(z + (size_t)row * DIM);
        *(float4*)&zs[w][lane * 8]     = zr[lane * 2];
        *(float4*)&zs[w][lane * 8 + 4] = zr[lane * 2 + 1];
        __syncthreads();

        unsigned long long best = ~0ull;
#pragma unroll
        for (int rr = 0; rr < 2; ++rr) {
            int code = base + rr * 64 + lane;
            const float4* c4 = (const float4*)(cb + (size_t)code * DIM);
            float s0 = 0.f, s1 = 0.f, s2 = 0.f, s3 = 0.f;
#pragma unroll 4
            for (int i = 0; i < 128; ++i) {
                float4 b = c4[i];
                float4 a = *(const float4*)&zs[w][i * 4];
                s0 += a.x * b.x; s1 += a.y * b.y;
                s2 += a.z * b.z; s3 += a.w * b.w;
            }
            float s = (s0 + s1) + (s2 + s3);
            float kv = -hne2[code] - s;        // = e2/2 - x.e  (> 0)
            unsigned long long key =
                ((unsigned long long)__float_as_uint(kv) << 32) |
                (unsigned long long)(unsigned)code;
            best = best < key ? best : key;
        }
#pragma unroll
        for (int off = 1; off <= 32; off <<= 1) {
            unsigned long long o = __shfl_xor(best, off, 64);
            best = best < o ? best : o;
        }
        if (active && lane == 0) atomicMin(&keys[row], best);
    }
}

// ---------------------------------------------------------------------------
// Kernel 5: final per-row results: index, counts, loss partial, z_q gather.
// ---------------------------------------------------------------------------
__global__ __launch_bounds__(256) void vq_final(
    const float* __restrict__ gBest, const int* __restrict__ provIdx,
    const int* __restrict__ flags, const unsigned long long* __restrict__ keys,
    const float* __restrict__ x2, const float* __restrict__ cb,
    float* __restrict__ zq, float* __restrict__ idxf,
    float* __restrict__ counts, float* __restrict__ lossAcc) {
    __shared__ int   sIdx[256];
    __shared__ float wsum[4];
    const int tid = threadIdx.x;
    const int r   = blockIdx.x * 256 + tid;

    int n; float dist;
    if (flags[r]) {
        unsigned long long k = keys[r];
        n = (int)(unsigned)(k & 0xffffffffu);
        float kv = __uint_as_float((unsigned)(k >> 32));
        dist = x2[r] + 2.0f * kv;          // x2 + e2 - 2 x.e
    } else {
        n = provIdx[r];
        dist = x2[r] - 2.0f * gBest[r];
    }
    sIdx[tid] = n;
    idxf[r]   = (float)n;
    atomicAdd(&counts[n], 1.0f);

    float ls = dist;
#pragma unroll
    for (int off = 32; off >= 1; off >>= 1) ls += __shfl_xor(ls, off, 64);
    if ((tid & 63) == 0) wsum[tid >> 6] = ls;
    __syncthreads();
    if (tid == 0) atomicAdd(lossAcc, wsum[0] + wsum[1] + wsum[2] + wsum[3]);

    const float4* cb4 = (const float4*)cb;
    float4* zq4 = (float4*)(zq + (size_t)blockIdx.x * 256 * DIM);
    for (int t = tid; t < 256 * (DIM / 4); t += 256) {
        int row = t >> 7, f4 = t & 127;
        zq4[(size_t)row * 128 + f4] = cb4[(size_t)sIdx[row] * 128 + f4];
    }
}

// ---------------------------------------------------------------------------
// Kernel 6: finalize scalars
// ---------------------------------------------------------------------------
__global__ __launch_bounds__(256) void vq_finalize(const float* __restrict__ counts,
                                                   const float* __restrict__ lossAcc,
                                                   float* __restrict__ out_loss,
                                                   float* __restrict__ out_perp) {
    __shared__ float wsum[4];
    int tid = threadIdx.x;
    float s = 0.0f;
    for (int i = tid; i < K_CODES; i += 256) {
        float p = counts[i] * (1.0f / (float)N_VEC);
        s += p * logf(p + 1e-10f);
    }
#pragma unroll
    for (int off = 32; off >= 1; off >>= 1) s += __shfl_xor(s, off, 64);
    if ((tid & 63) == 0) wsum[tid >> 6] = s;
    __syncthreads();
    if (tid == 0) {
        *out_perp = expf(-(wsum[0] + wsum[1] + wsum[2] + wsum[3]));
        *out_loss = 1.25f * lossAcc[0] / (float)(N_VEC * DIM);
    }
}

// ---------------------------------------------------------------------------
// ws layout (bytes), total ~61 MB:
//   x2 @0 131072 | hne2 @131072 32768 | counts @163840 32768 | lossAcc @196608 4
//   poolCnt @196612 4 | provIdx @262144 131072 | flags @393216 131072
//   keys @524288 262144 | pool @786432 8388608 (worst case 2.1M entries)
//   pG @9175040 524288 | pN @9699328 524288 | pG2 @10223616 524288
//   pT @10747904 8388608 | zh @19136512 33554432 | ch @52690944 8388608
// ---------------------------------------------------------------------------
extern "C" void kernel_launch(void* const* d_in, const int* in_sizes, int n_in,
                              void* d_out, int out_size, void* d_ws, size_t ws_size,
                              hipStream_t stream) {
    (void)in_sizes; (void)n_in; (void)out_size; (void)ws_size;
    const float* z  = (const float*)d_in[0];
    const float* cb = (const float*)d_in[1];

    char* ws = (char*)d_ws;
    float* x2        = (float*)(ws + 0);
    float* hne2      = (float*)(ws + 131072);
    float* counts    = (float*)(ws + 163840);
    float* lossAcc   = (float*)(ws + 196608);
    int*   poolCnt   = (int*)  (ws + 196612);
    int*   provIdx   = (int*)  (ws + 262144);
    int*   flags     = (int*)  (ws + 393216);
    unsigned long long* keys = (unsigned long long*)(ws + 524288);
    int*   pool      = (int*)  (ws + 786432);
    float* pG        = (float*)(ws + 9175040);
    int*   pN        = (int*)  (ws + 9699328);
    float* pG2       = (float*)(ws + 10223616);
    float* pT        = (float*)(ws + 10747904);
    unsigned short* zh = (unsigned short*)(ws + 19136512);
    unsigned short* ch = (unsigned short*)(ws + 52690944);

    float* out      = (float*)d_out;
    float* zq       = out;
    float* out_loss = out + 16777216;
    float* idxf     = out + 16777217;
    float* out_perp = out + 16777217 + 32768;

    // zero counts + lossAcc + poolCnt (contiguous)
    hipMemsetAsync(counts, 0, 32768 + 8, stream);
    vq_prep<<<(N_VEC + K_CODES) / 4, 256, 0, stream>>>(z, cb, x2, hne2, zh, ch);
    dim3 grid(N_VEC / 128, 2);
    vq_gemm<<<grid, 256, 0, stream>>>(zh, ch, hne2, pG, pN, pG2, pT);
    vq_scan<<<N_VEC / 256, 256, 0, stream>>>(pG, pN, pG2, pT, provIdx, flags,
                                             keys, pool, poolCnt);
    vq_rescue<<<512, 256, 0, stream>>>(z, cb, hne2, pool, poolCnt, keys);
    vq_final<<<N_VEC / 256, 256, 0, stream>>>(pG, provIdx, flags, keys, x2, cb,
                                              zq, idxf, counts, lossAcc);
    vq_finalize<<<1, 256, 0, stream>>>(counts, lossAcc, out_loss, out_perp);
}

// Round 6
// 728.025 us; speedup vs baseline: 1.0058x; 1.0058x over previous
//
#include <hip/hip_runtime.h>
#include <hip/hip_bf16.h>

#define K_CODES 8192
#define DIM     512
#define N_VEC   32768
#define MARGIN  0.35f   // level-1 flag threshold on g = x.e - e2/2 (bf16 error ~10 sigma)
#define MARGIN2 0.02f   // level-2 threshold (split-bf16 error ~60 sigma)

typedef __attribute__((ext_vector_type(8))) short   short8;   // bf16x8 MFMA operand
typedef __attribute__((ext_vector_type(8))) unsigned short ushort8;
typedef __attribute__((ext_vector_type(4))) float   float4x;  // MFMA C/D frag

// async global->LDS, 16 B/lane. LDS dest = wave-uniform base + lane*16.
__device__ inline void gl_lds16(const void* g, void* l) {
    __builtin_amdgcn_global_load_lds(
        (const __attribute__((address_space(1))) unsigned int*)g,
        (__attribute__((address_space(3))) unsigned int*)l, 16, 0, 0);
}

// fp32 -> bf16 bits, round-to-nearest-even; *back = rounded-back float
__device__ inline unsigned short f2bf(float f, float* back) {
    unsigned int u = __float_as_uint(f);
    unsigned int r = (u + 0x7FFFu + ((u >> 16) & 1u)) >> 16;
    *back = __uint_as_float(r << 16);
    return (unsigned short)r;
}

// ---------------------------------------------------------------------------
// Kernel 1: prep. rows [0,N_VEC) from z -> zh/zl + x2 ; rows [N_VEC,+K) from
// cb -> ch/cl + hne2 = -0.5*||e||^2.  One wave per row.
// ---------------------------------------------------------------------------
__global__ __launch_bounds__(256) void vq_prep(
    const float* __restrict__ z, const float* __restrict__ cb,
    float* __restrict__ x2, float* __restrict__ hne2,
    unsigned short* __restrict__ zh, unsigned short* __restrict__ zl,
    unsigned short* __restrict__ ch, unsigned short* __restrict__ cl) {
    int wave = threadIdx.x >> 6;
    int lane = threadIdx.x & 63;
    int row  = blockIdx.x * 4 + wave;
    bool isZ = row < N_VEC;
    int lr = isZ ? row : row - N_VEC;
    const float* src = isZ ? z + (size_t)row * DIM : cb + (size_t)lr * DIM;

    const float4* s4 = (const float4*)src;
    float4 v0 = s4[lane * 2];
    float4 v1 = s4[lane * 2 + 1];
    float f[8] = {v0.x, v0.y, v0.z, v0.w, v1.x, v1.y, v1.z, v1.w};

    float s = 0.0f;
    ushort8 h8, l8;
#pragma unroll
    for (int i = 0; i < 8; ++i) {
        s += f[i] * f[i];
        float back, dummy;
        h8[i] = f2bf(f[i], &back);
        l8[i] = f2bf(f[i] - back, &dummy);
    }
    ((ushort8*)(isZ ? zh : ch))[(size_t)lr * 64 + lane] = h8;
    ((ushort8*)(isZ ? zl : cl))[(size_t)lr * 64 + lane] = l8;

#pragma unroll
    for (int off = 32; off >= 1; off >>= 1) s += __shfl_xor(s, off, 64);
    if (lane == 0) {
        if (isZ) x2[lr] = s;
        else     hne2[lr] = -0.5f * s;
    }
}

// ---------------------------------------------------------------------------
// Kernel 2: bf16 MFMA GEMM + fused top-2 argmax of g = x.e - e2/2.
// (round-4 version verbatim — 287 us, MfmaUtil 43%, 0 conflicts)
// ---------------------------------------------------------------------------
__global__ __launch_bounds__(256, 2) void vq_gemm(
    const unsigned short* __restrict__ zh, const unsigned short* __restrict__ ch,
    const float* __restrict__ hne2,
    float* __restrict__ pG, int* __restrict__ pN, float* __restrict__ pG2) {
    __shared__ short8 AsC[1024];   // 128 rows x 8 octet-cells, XOR-swizzled (16 KB)
    __shared__ short8 BsC[2048];   // 256 codes x 8 octet-cells, XOR-swizzled (32 KB)

    const int tid  = threadIdx.x;
    const int w    = tid >> 6;
    const int lane = tid & 63;
    const int wM   = w & 1;
    const int wN   = w >> 1;
    const int rowBase   = blockIdx.x * 128;
    const int half      = blockIdx.y;
    const int codeBase0 = half * 4096;

    const int low3 = lane & 7, m15 = lane & 15, hi4 = lane >> 4;

    unsigned aOff[4];
#pragma unroll
    for (int i = 0; i < 4; ++i) {
        int cell = (w * 4 + i) * 64 + lane;
        int r = cell >> 3, qs = cell & 7, q = qs ^ (r & 7);
        aOff[i] = ((unsigned)(rowBase + r) * DIM + q * 8) * 2;
    }
    unsigned bOff[8];
#pragma unroll
    for (int i = 0; i < 8; ++i) {
        int cell = (w * 8 + i) * 64 + lane;
        int c = cell >> 3, qs = cell & 7, q = qs ^ (c & 7);
        bOff[i] = ((unsigned)c * DIM + q * 8) * 2;   // relative to code-tile base
    }

    int rIdx[4], cIdx[8];
#pragma unroll
    for (int mf = 0; mf < 4; ++mf) rIdx[mf] = (wM * 64 + mf * 16 + m15) * 8;
#pragma unroll
    for (int nf = 0; nf < 8; ++nf) cIdx[nf] = (wN * 128 + nf * 16 + m15) * 8;

    float g1[4][4], g2[4][4];
    int   n1[4][4];
#pragma unroll
    for (int mf = 0; mf < 4; ++mf)
#pragma unroll
        for (int rg = 0; rg < 4; ++rg) {
            g1[mf][rg] = -3.4e38f; g2[mf][rg] = -3.4e38f; n1[mf][rg] = 0;
        }

    const char* pA = (const char*)zh;
    for (int ct = 0; ct < 16; ++ct) {
        const int codeBase = codeBase0 + ct * 256;
        const char* pB = (const char*)ch + (size_t)codeBase * (DIM * 2);
        float4x acc[4][8];
#pragma unroll
        for (int mf = 0; mf < 4; ++mf)
#pragma unroll
            for (int nf = 0; nf < 8; ++nf) acc[mf][nf] = (float4x){0.f, 0.f, 0.f, 0.f};

        for (int dc = 0; dc < DIM; dc += 64) {
            const int dc2 = dc * 2;
            __syncthreads();
#pragma unroll
            for (int i = 0; i < 4; ++i)
                gl_lds16(pA + aOff[i] + dc2, &AsC[(w * 4 + i) * 64]);
#pragma unroll
            for (int i = 0; i < 8; ++i)
                gl_lds16(pB + bOff[i] + dc2, &BsC[(w * 8 + i) * 64]);
            __syncthreads();

#pragma unroll
            for (int ks = 0; ks < 2; ++ks) {
                const int qx = (ks * 4 + hi4) ^ low3;
                short8 a[4];
#pragma unroll
                for (int mf = 0; mf < 4; ++mf) a[mf] = AsC[rIdx[mf] + qx];
#pragma unroll
                for (int nf = 0; nf < 8; ++nf) {
                    short8 b = BsC[cIdx[nf] + qx];
#pragma unroll
                    for (int mf = 0; mf < 4; ++mf)
                        acc[mf][nf] = __builtin_amdgcn_mfma_f32_16x16x32_bf16(
                            a[mf], b, acc[mf][nf], 0, 0, 0);
                }
            }
        }

        // epilogue: running top-2 of g (ties -> g2=g1 -> gap 0 -> rescued)
#pragma unroll
        for (int nf = 0; nf < 8; ++nf) {
            int nb = codeBase + wN * 128 + nf * 16 + m15;
            float hv = hne2[nb];
#pragma unroll
            for (int mf = 0; mf < 4; ++mf) {
#pragma unroll
                for (int rg = 0; rg < 4; ++rg) {
                    float g = acc[mf][nf][rg] + hv;
                    if (g > g1[mf][rg]) {
                        g2[mf][rg] = g1[mf][rg];
                        g1[mf][rg] = g; n1[mf][rg] = nb;
                    } else {
                        g2[mf][rg] = fmaxf(g2[mf][rg], g);
                    }
                }
            }
        }
    }

    // cross-lane top-2 merge over the 16 lanes sharing each row
#pragma unroll
    for (int mf = 0; mf < 4; ++mf)
#pragma unroll
        for (int rg = 0; rg < 4; ++rg) {
            float a1 = g1[mf][rg], a2 = g2[mf][rg];
            int   an = n1[mf][rg];
#pragma unroll
            for (int off = 1; off <= 8; off <<= 1) {
                float b1 = __shfl_xor(a1, off, 64);
                int   bn = __shfl_xor(an, off, 64);
                float b2 = __shfl_xor(a2, off, 64);
                if (b1 > a1 || (b1 == a1 && bn < an)) {
                    a2 = fmaxf(a1, b2); a1 = b1; an = bn;
                } else {
                    a2 = fmaxf(a2, b1);
                }
            }
            if (m15 == 0) {
                int row  = rowBase + wM * 64 + mf * 16 + hi4 * 4 + rg;
                int slot = half * 2 + wN;          // unique per (block.y, wave-col)
                pG [slot * N_VEC + row] = a1;
                pN [slot * N_VEC + row] = an;
                pG2[slot * N_VEC + row] = a2;
            }
        }
}

// ---------------------------------------------------------------------------
// Kernel 3: merge 4 partial slots per row, flag near-ties, compact flagged
// rows into rescueRows. (round-4 version)
// ---------------------------------------------------------------------------
__global__ __launch_bounds__(256) void vq_scan(
    float* __restrict__ pG, const int* __restrict__ pN,
    const float* __restrict__ pG2,
    int* __restrict__ provIdx, int* __restrict__ flags,
    unsigned long long* __restrict__ keys,
    int* __restrict__ rescueRows, int* __restrict__ rescueCnt) {
    int r = blockIdx.x * 256 + threadIdx.x;
    float g1 = pG[r], g2 = pG2[r];
    int   n1 = pN[r];
#pragma unroll
    for (int s = 1; s < 4; ++s) {
        float a1 = pG [s * N_VEC + r];
        int   an = pN [s * N_VEC + r];
        float a2 = pG2[s * N_VEC + r];
        if (a1 > g1 || (a1 == g1 && an < n1)) {
            g2 = fmaxf(g1, a2); g1 = a1; n1 = an;
        } else {
            g2 = fmaxf(g2, a1);
        }
    }
    provIdx[r] = n1;
    pG[r] = g1;                       // merged best (for loss)
    int fl = (g1 - g2 < MARGIN) ? 1 : 0;
    flags[r] = fl;
    if (fl) {
        keys[r] = ~0ull;
        int p = atomicAdd(rescueCnt, 1);
        rescueRows[p] = r;
    }
}

// ---------------------------------------------------------------------------
// Kernel 4: MID rescue — split-bf16 MFMA over flagged rows (indirected).
// x ~= xh+xl, e ~= eh+el; 3 passes xh.eh + xl.eh + xh.el; residual (xl.el +
// repr + accum) ~3e-4 sigma. Block = 64 compact rows x 1024 codes
// (blockIdx.y*1024), persistent over row-tiles (grid.x=32 stride). 4 waves
// 2x2: wave tile 32 rows x 128 codes (2 M-frags x 8 N-frags). Per-row top-2
// kept across the 4 code-tiles; partials to slot = blockIdx.y*2 + wN (16).
// rescueRows zero-padded so slots >= cnt harmlessly compute row 0.
// ---------------------------------------------------------------------------
__global__ __launch_bounds__(256, 2) void vq_mid(
    const unsigned short* __restrict__ zh, const unsigned short* __restrict__ zl,
    const unsigned short* __restrict__ ch, const unsigned short* __restrict__ cl,
    const float* __restrict__ hne2,
    const int* __restrict__ rescueRows, const int* __restrict__ rescueCnt,
    float* __restrict__ pGm, int* __restrict__ pNm, float* __restrict__ pG2m) {
    __shared__ short8 AsC[512];    // 64 rows x 8 octet-cells, XOR-swizzled (8 KB)
    __shared__ short8 BsC[2048];   // 256 codes x 8 octet-cells (32 KB)
    __shared__ int rowOf[64];

    const int tid  = threadIdx.x;
    const int w    = tid >> 6;
    const int lane = tid & 63;
    const int wM   = w & 1;        // row-half: 32 rows
    const int wN   = w >> 1;       // code-half: 128 codes
    const int cnt  = *rescueCnt;
    const int codeBase0 = blockIdx.y * 1024;

    const int low3 = lane & 7, m15 = lane & 15, hi4 = lane >> 4;

    unsigned bOff[8];
#pragma unroll
    for (int i = 0; i < 8; ++i) {
        int cell = (w * 8 + i) * 64 + lane;
        int c = cell >> 3, qs = cell & 7, q = qs ^ (c & 7);
        bOff[i] = ((unsigned)c * DIM + q * 8) * 2;   // relative to code-tile base
    }
    int aCellR[2], aCellQ[2];
#pragma unroll
    for (int i = 0; i < 2; ++i) {
        int cell = (w * 2 + i) * 64 + lane;
        aCellR[i] = cell >> 3;
        aCellQ[i] = (cell & 7) ^ (aCellR[i] & 7);
    }

    int rIdx[2], cIdx[8];
#pragma unroll
    for (int mf = 0; mf < 2; ++mf) rIdx[mf] = (wM * 32 + mf * 16 + m15) * 8;
#pragma unroll
    for (int nf = 0; nf < 8; ++nf) cIdx[nf] = (wN * 128 + nf * 16 + m15) * 8;

    for (int rt = blockIdx.x; rt * 64 < cnt; rt += gridDim.x) {
        __syncthreads();   // prior iteration fully done
        if (tid < 64) rowOf[tid] = rescueRows[rt * 64 + tid];
        __syncthreads();

        unsigned aOff[2];
#pragma unroll
        for (int i = 0; i < 2; ++i)
            aOff[i] = ((unsigned)rowOf[aCellR[i]] * DIM + aCellQ[i] * 8) * 2;

        float g1[2][4], g2[2][4];
        int   n1[2][4];
#pragma unroll
        for (int mf = 0; mf < 2; ++mf)
#pragma unroll
            for (int rg = 0; rg < 4; ++rg) {
                g1[mf][rg] = -3.4e38f; g2[mf][rg] = -3.4e38f; n1[mf][rg] = 0;
            }

        for (int ct = 0; ct < 4; ++ct) {
            const int codeBase = codeBase0 + ct * 256;
            float4x acc[2][8];
#pragma unroll
            for (int mf = 0; mf < 2; ++mf)
#pragma unroll
                for (int nf = 0; nf < 8; ++nf) acc[mf][nf] = (float4x){0.f, 0.f, 0.f, 0.f};

#pragma unroll
            for (int pass = 0; pass < 3; ++pass) {
                const char* pA = (const char*)(pass == 1 ? zl : zh);
                const char* pB = (const char*)(pass == 2 ? cl : ch)
                                 + (size_t)codeBase * (DIM * 2);
                for (int dc = 0; dc < DIM; dc += 64) {
                    const int dc2 = dc * 2;
                    __syncthreads();
#pragma unroll
                    for (int i = 0; i < 2; ++i)
                        gl_lds16(pA + aOff[i] + dc2, &AsC[(w * 2 + i) * 64]);
#pragma unroll
                    for (int i = 0; i < 8; ++i)
                        gl_lds16(pB + bOff[i] + dc2, &BsC[(w * 8 + i) * 64]);
                    __syncthreads();

#pragma unroll
                    for (int ks = 0; ks < 2; ++ks) {
                        const int qx = (ks * 4 + hi4) ^ low3;
                        short8 a[2];
#pragma unroll
                        for (int mf = 0; mf < 2; ++mf) a[mf] = AsC[rIdx[mf] + qx];
#pragma unroll
                        for (int nf = 0; nf < 8; ++nf) {
                            short8 b = BsC[cIdx[nf] + qx];
#pragma unroll
                            for (int mf = 0; mf < 2; ++mf)
                                acc[mf][nf] = __builtin_amdgcn_mfma_f32_16x16x32_bf16(
                                    a[mf], b, acc[mf][nf], 0, 0, 0);
                        }
                    }
                }
            }

            // top-2 update
#pragma unroll
            for (int nf = 0; nf < 8; ++nf) {
                int nb = codeBase + wN * 128 + nf * 16 + m15;
                float hv = hne2[nb];
#pragma unroll
                for (int mf = 0; mf < 2; ++mf) {
#pragma unroll
                    for (int rg = 0; rg < 4; ++rg) {
                        float g = acc[mf][nf][rg] + hv;
                        if (g > g1[mf][rg]) {
                            g2[mf][rg] = g1[mf][rg];
                            g1[mf][rg] = g; n1[mf][rg] = nb;
                        } else {
                            g2[mf][rg] = fmaxf(g2[mf][rg], g);
                        }
                    }
                }
            }
        }

        // cross-lane top-2 merge + partial write (slot = blockIdx.y*2 + wN)
#pragma unroll
        for (int mf = 0; mf < 2; ++mf)
#pragma unroll
            for (int rg = 0; rg < 4; ++rg) {
                float a1 = g1[mf][rg], a2 = g2[mf][rg];
                int   an = n1[mf][rg];
#pragma unroll
                for (int off = 1; off <= 8; off <<= 1) {
                    float b1 = __shfl_xor(a1, off, 64);
                    int   bn = __shfl_xor(an, off, 64);
                    float b2 = __shfl_xor(a2, off, 64);
                    if (b1 > a1 || (b1 == a1 && bn < an)) {
                        a2 = fmaxf(a1, b2); a1 = b1; an = bn;
                    } else {
                        a2 = fmaxf(a2, b1);
                    }
                }
                if (m15 == 0) {
                    int sPos = rt * 64 + wM * 32 + mf * 16 + hi4 * 4 + rg;
                    int slot = blockIdx.y * 2 + wN;
                    pGm [slot * N_VEC + sPos] = a1;
                    pNm [slot * N_VEC + sPos] = an;
                    pG2m[slot * N_VEC + sPos] = a2;
                }
            }
    }
}

// ---------------------------------------------------------------------------
// Kernel 5: merge 16 mid slots per compact row; escalate gap<MARGIN2 rows to
// exact rescue, else write final key (kv = e2/2 - x.e packed with code).
// ---------------------------------------------------------------------------
__global__ __launch_bounds__(256) void vq_scan2(
    const float* __restrict__ pGm, const int* __restrict__ pNm,
    const float* __restrict__ pG2m,
    const int* __restrict__ rescueRows, const int* __restrict__ rescueCnt,
    unsigned long long* __restrict__ keys,
    int* __restrict__ rescueRows2, int* __restrict__ rescueCnt2) {
    int s = blockIdx.x * 256 + threadIdx.x;
    if (s >= *rescueCnt) return;
    float g1 = pGm[s], g2 = pG2m[s];
    int   n1 = pNm[s];
#pragma unroll
    for (int k = 1; k < 16; ++k) {
        float a1 = pGm [k * N_VEC + s];
        int   an = pNm [k * N_VEC + s];
        float a2 = pG2m[k * N_VEC + s];
        if (a1 > g1 || (a1 == g1 && an < n1)) {
            g2 = fmaxf(g1, a2); g1 = a1; n1 = an;
        } else {
            g2 = fmaxf(g2, a1);
        }
    }
    int row = rescueRows[s];
    if (g1 - g2 < MARGIN2) {
        keys[row] = ~0ull;
        int p = atomicAdd(rescueCnt2, 1);
        rescueRows2[p] = row;
    } else {
        keys[row] = ((unsigned long long)__float_as_uint(-g1) << 32) |
                    (unsigned long long)(unsigned)n1;
    }
}

// ---------------------------------------------------------------------------
// Kernel 6: exact fp32 rescue over escalated rows (round-4 kernel; expected
// cnt2 ~ tens). 64 slots x 512 codes per block, persistent over row-tiles.
// ---------------------------------------------------------------------------
#define RBM 64
#define RBK 256
#define RBD 32

__global__ __launch_bounds__(256, 2) void vq_exact(
    const float* __restrict__ z, const float* __restrict__ cb,
    const float* __restrict__ hne2,
    const int* __restrict__ rescueRows2, const int* __restrict__ rescueCnt2,
    unsigned long long* __restrict__ keys) {
    __shared__ float As[RBD][RBM];   // 8 KB, transposed
    __shared__ float Bs[RBD][RBK];   // 32 KB, transposed
    __shared__ int   rowOf[RBM];

    const int tid = threadIdx.x;
    const int tx  = tid & 31;
    const int ty  = tid >> 5;
    const int cnt = *rescueCnt2;
    const int codeBase0 = blockIdx.y * 512;      // grid.y = 16
    const int sw = (tx & 8) ? 4 : 0;
    const int sRow = tid >> 2;
    const int sQ   = tid & 3;

    for (int rt = blockIdx.x; rt * RBM < cnt; rt += gridDim.x) {
        const int slotBase = rt * RBM;
        __syncthreads();
        if (tid < RBM) rowOf[tid] = rescueRows2[slotBase + tid];
        __syncthreads();

        float best[8];
        int   bidx[8];
#pragma unroll
        for (int i = 0; i < 8; ++i) { best[i] = 3.4e38f; bidx[i] = K_CODES; }

        for (int kt = 0; kt < 2; ++kt) {
            const int codeBase = codeBase0 + kt * RBK;
            float acc[8][8];
#pragma unroll
            for (int i = 0; i < 8; ++i)
#pragma unroll
                for (int j = 0; j < 8; ++j) acc[i][j] = 0.0f;

            for (int dc = 0; dc < DIM; dc += RBD) {
                __syncthreads();
                {
                    const float* srcA = z + (size_t)rowOf[sRow] * DIM + dc + sQ * 8;
                    float4 va0 = ((const float4*)srcA)[0];
                    float4 va1 = ((const float4*)srcA)[1];
                    int c0 = sQ * 8;
                    As[c0 + 0][sRow] = va0.x; As[c0 + 1][sRow] = va0.y;
                    As[c0 + 2][sRow] = va0.z; As[c0 + 3][sRow] = va0.w;
                    As[c0 + 4][sRow] = va1.x; As[c0 + 5][sRow] = va1.y;
                    As[c0 + 6][sRow] = va1.z; As[c0 + 7][sRow] = va1.w;
                }
                {
                    const float4* srcB = (const float4*)(cb + (size_t)(codeBase + tid) * DIM + dc);
#pragma unroll
                    for (int j = 0; j < 8; ++j) {
                        float4 v = srcB[j];
                        Bs[j * 4 + 0][tid] = v.x; Bs[j * 4 + 1][tid] = v.y;
                        Bs[j * 4 + 2][tid] = v.z; Bs[j * 4 + 3][tid] = v.w;
                    }
                }
                __syncthreads();

#pragma unroll
                for (int d = 0; d < RBD; ++d) {
                    float a[8], b[8];
                    *(float4*)&a[0] = *(const float4*)&As[d][ty * 8];
                    *(float4*)&a[4] = *(const float4*)&As[d][ty * 8 + 4];
                    *(float4*)&b[0] = *(const float4*)&Bs[d][tx * 8 + sw];
                    *(float4*)&b[4] = *(const float4*)&Bs[d][tx * 8 + (sw ^ 4)];
#pragma unroll
                    for (int i = 0; i < 8; ++i)
#pragma unroll
                        for (int j = 0; j < 8; ++j) acc[i][j] += a[i] * b[j];
                }
            }

#pragma unroll
            for (int j = 0; j < 8; ++j) {
                int code = codeBase + tx * 8 + ((j < 4) ? (sw + j) : ((sw ^ 4) + j - 4));
                float ev = -hne2[code];           // = e2/2
#pragma unroll
                for (int i = 0; i < 8; ++i) {
                    float kv = ev - acc[i][j];    // = e2/2 - x.e  (> 0)
                    if (kv < best[i] || (kv == best[i] && code < bidx[i])) {
                        best[i] = kv;
                        bidx[i] = code;
                    }
                }
            }
        }

#pragma unroll
        for (int off = 16; off >= 1; off >>= 1) {
#pragma unroll
            for (int i = 0; i < 8; ++i) {
                float od = __shfl_xor(best[i], off, 64);
                int   oi = __shfl_xor(bidx[i], off, 64);
                if (od < best[i] || (od == best[i] && oi < bidx[i])) {
                    best[i] = od;
                    bidx[i] = oi;
                }
            }
        }

        if (tx == 0) {
#pragma unroll
            for (int i = 0; i < 8; ++i) {
                int slot = slotBase + ty * 8 + i;
                if (slot < cnt) {
                    unsigned long long key =
                        ((unsigned long long)__float_as_uint(best[i]) << 32) |
                        (unsigned long long)(unsigned)bidx[i];
                    atomicMin(&keys[rowOf[ty * 8 + i]], key);
                }
            }
        }
    }
}

// ---------------------------------------------------------------------------
// Kernel 7: final per-row results: index, counts, loss partial, z_q gather.
// ---------------------------------------------------------------------------
__global__ __launch_bounds__(256) void vq_final(
    const float* __restrict__ gBest, const int* __restrict__ provIdx,
    const int* __restrict__ flags, const unsigned long long* __restrict__ keys,
    const float* __restrict__ x2, const float* __restrict__ cb,
    float* __restrict__ zq, float* __restrict__ idxf,
    float* __restrict__ counts, float* __restrict__ lossAcc) {
    __shared__ int   sIdx[256];
    __shared__ float wsum[4];
    const int tid = threadIdx.x;
    const int r   = blockIdx.x * 256 + tid;

    int n; float dist;
    if (flags[r]) {
        unsigned long long k = keys[r];
        n = (int)(unsigned)(k & 0xffffffffu);
        float kv = __uint_as_float((unsigned)(k >> 32));
        dist = x2[r] + 2.0f * kv;          // x2 + e2 - 2 x.e
    } else {
        n = provIdx[r];
        dist = x2[r] - 2.0f * gBest[r];
    }
    sIdx[tid] = n;
    idxf[r]   = (float)n;
    atomicAdd(&counts[n], 1.0f);

    float ls = dist;
#pragma unroll
    for (int off = 32; off >= 1; off >>= 1) ls += __shfl_xor(ls, off, 64);
    if ((tid & 63) == 0) wsum[tid >> 6] = ls;
    __syncthreads();
    if (tid == 0) atomicAdd(lossAcc, wsum[0] + wsum[1] + wsum[2] + wsum[3]);

    const float4* cb4 = (const float4*)cb;
    float4* zq4 = (float4*)(zq + (size_t)blockIdx.x * 256 * DIM);
    for (int t = tid; t < 256 * (DIM / 4); t += 256) {
        int row = t >> 7, f4 = t & 127;
        zq4[(size_t)row * 128 + f4] = cb4[(size_t)sIdx[row] * 128 + f4];
    }
}

// ---------------------------------------------------------------------------
// Kernel 8: finalize scalars
// ---------------------------------------------------------------------------
__global__ __launch_bounds__(256) void vq_finalize(const float* __restrict__ counts,
                                                   const float* __restrict__ lossAcc,
                                                   float* __restrict__ out_loss,
                                                   float* __restrict__ out_perp) {
    __shared__ float wsum[4];
    int tid = threadIdx.x;
    float s = 0.0f;
    for (int i = tid; i < K_CODES; i += 256) {
        float p = counts[i] * (1.0f / (float)N_VEC);
        s += p * logf(p + 1e-10f);
    }
#pragma unroll
    for (int off = 32; off >= 1; off >>= 1) s += __shfl_xor(s, off, 64);
    if ((tid & 63) == 0) wsum[tid >> 6] = s;
    __syncthreads();
    if (tid == 0) {
        *out_perp = expf(-(wsum[0] + wsum[1] + wsum[2] + wsum[3]));
        *out_loss = 1.25f * lossAcc[0] / (float)(N_VEC * DIM);
    }
}

// ---------------------------------------------------------------------------
// ws layout (bytes), total ~93 MB:
//   x2 @0 131072 | hne2 @131072 32768 | counts @163840 32768
//   lossAcc @196608 4 | rescueCnt @196612 4 | rescueCnt2 @196616 4
//   provIdx @262144 131072 | flags @393216 131072 | keys @524288 262144
//   rescueRows @786432 131072 | rescueRows2 @917504 131072
//   pG @1048576 524288 | pN @1572864 524288 | pG2 @2097152 524288
//   pGm @2621440 2097152 | pNm @4718592 2097152 | pG2m @6815744 2097152
//   zh @8912896 33554432 | zl @42467328 33554432
//   ch @76021760 8388608 | cl @84410368 8388608  -> end 92798976
// ---------------------------------------------------------------------------
extern "C" void kernel_launch(void* const* d_in, const int* in_sizes, int n_in,
                              void* d_out, int out_size, void* d_ws, size_t ws_size,
                              hipStream_t stream) {
    (void)in_sizes; (void)n_in; (void)out_size; (void)ws_size;
    const float* z  = (const float*)d_in[0];
    const float* cb = (const float*)d_in[1];

    char* ws = (char*)d_ws;
    float* x2         = (float*)(ws + 0);
    float* hne2       = (float*)(ws + 131072);
    float* counts     = (float*)(ws + 163840);
    float* lossAcc    = (float*)(ws + 196608);
    int*   rescueCnt  = (int*)  (ws + 196612);
    int*   rescueCnt2 = (int*)  (ws + 196616);
    int*   provIdx    = (int*)  (ws + 262144);
    int*   flags      = (int*)  (ws + 393216);
    unsigned long long* keys = (unsigned long long*)(ws + 524288);
    int*   rescueRows  = (int*)(ws + 786432);
    int*   rescueRows2 = (int*)(ws + 917504);
    float* pG         = (float*)(ws + 1048576);
    int*   pN         = (int*)  (ws + 1572864);
    float* pG2        = (float*)(ws + 2097152);
    float* pGm        = (float*)(ws + 2621440);
    int*   pNm        = (int*)  (ws + 4718592);
    float* pG2m       = (float*)(ws + 6815744);
    unsigned short* zh = (unsigned short*)(ws + 8912896);
    unsigned short* zl = (unsigned short*)(ws + 42467328);
    unsigned short* ch = (unsigned short*)(ws + 76021760);
    unsigned short* cl = (unsigned short*)(ws + 84410368);

    float* out      = (float*)d_out;
    float* zq       = out;
    float* out_loss = out + 16777216;
    float* idxf     = out + 16777217;
    float* out_perp = out + 16777217 + 32768;

    // zero counts + lossAcc + rescueCnt + rescueCnt2 (contiguous), and the
    // two rescue-row lists (zero-padding for the indirected tiles)
    hipMemsetAsync(counts, 0, 32768 + 12, stream);
    hipMemsetAsync(rescueRows, 0, 262144, stream);
    vq_prep<<<(N_VEC + K_CODES) / 4, 256, 0, stream>>>(z, cb, x2, hne2, zh, zl, ch, cl);
    dim3 grid(N_VEC / 128, 2);
    vq_gemm<<<grid, 256, 0, stream>>>(zh, ch, hne2, pG, pN, pG2);
    vq_scan<<<N_VEC / 256, 256, 0, stream>>>(pG, pN, pG2, provIdx, flags, keys,
                                             rescueRows, rescueCnt);
    dim3 mgrid(32, 8);
    vq_mid<<<mgrid, 256, 0, stream>>>(zh, zl, ch, cl, hne2, rescueRows, rescueCnt,
                                      pGm, pNm, pG2m);
    vq_scan2<<<N_VEC / 256, 256, 0, stream>>>(pGm, pNm, pG2m, rescueRows, rescueCnt,
                                              keys, rescueRows2, rescueCnt2);
    dim3 egrid(8, 16);
    vq_exact<<<egrid, 256, 0, stream>>>(z, cb, hne2, rescueRows2, rescueCnt2, keys);
    vq_final<<<N_VEC / 256, 256, 0, stream>>>(pG, provIdx, flags, keys, x2, cb,
                                              zq, idxf, counts, lossAcc);
    vq_finalize<<<1, 256, 0, stream>>>(counts, lossAcc, out_loss, out_perp);
}

// Round 7
// 686.753 us; speedup vs baseline: 1.0662x; 1.0601x over previous
//
#include <hip/hip_runtime.h>
#include <hip/hip_bf16.h>

#define K_CODES 8192
#define DIM     512
#define N_VEC   32768
#define MARGIN  0.35f   // level-1 flag threshold on g = x.e - e2/2 (bf16 error ~10 sigma)
#define MARGIN2 0.02f   // level-2 threshold (split-bf16 error ~60 sigma)
#define MAXC    8192    // compact-row capacity of the mid rescue (overflow -> exact)

typedef __attribute__((ext_vector_type(8))) short   short8;   // bf16x8 MFMA operand
typedef __attribute__((ext_vector_type(8))) unsigned short ushort8;
typedef __attribute__((ext_vector_type(4))) float   float4x;  // MFMA C/D frag

// async global->LDS, 16 B/lane. LDS dest = wave-uniform base + lane*16.
__device__ inline void gl_lds16(const void* g, void* l) {
    __builtin_amdgcn_global_load_lds(
        (const __attribute__((address_space(1))) unsigned int*)g,
        (__attribute__((address_space(3))) unsigned int*)l, 16, 0, 0);
}

// fp32 -> bf16 bits, round-to-nearest-even; *back = rounded-back float
__device__ inline unsigned short f2bf(float f, float* back) {
    unsigned int u = __float_as_uint(f);
    unsigned int r = (u + 0x7FFFu + ((u >> 16) & 1u)) >> 16;
    *back = __uint_as_float(r << 16);
    return (unsigned short)r;
}

// ---------------------------------------------------------------------------
// Kernel 1: prep. rows [0,N_VEC) from z -> zh/zl + x2 ; rows [N_VEC,+K) from
// cb -> ch/cl + hne2 = -0.5*||e||^2.  One wave per row.
// ---------------------------------------------------------------------------
__global__ __launch_bounds__(256) void vq_prep(
    const float* __restrict__ z, const float* __restrict__ cb,
    float* __restrict__ x2, float* __restrict__ hne2,
    unsigned short* __restrict__ zh, unsigned short* __restrict__ zl,
    unsigned short* __restrict__ ch, unsigned short* __restrict__ cl) {
    int wave = threadIdx.x >> 6;
    int lane = threadIdx.x & 63;
    int row  = blockIdx.x * 4 + wave;
    bool isZ = row < N_VEC;
    int lr = isZ ? row : row - N_VEC;
    const float* src = isZ ? z + (size_t)row * DIM : cb + (size_t)lr * DIM;

    const float4* s4 = (const float4*)src;
    float4 v0 = s4[lane * 2];
    float4 v1 = s4[lane * 2 + 1];
    float f[8] = {v0.x, v0.y, v0.z, v0.w, v1.x, v1.y, v1.z, v1.w};

    float s = 0.0f;
    ushort8 h8, l8;
#pragma unroll
    for (int i = 0; i < 8; ++i) {
        s += f[i] * f[i];
        float back, dummy;
        h8[i] = f2bf(f[i], &back);
        l8[i] = f2bf(f[i] - back, &dummy);
    }
    ((ushort8*)(isZ ? zh : ch))[(size_t)lr * 64 + lane] = h8;
    ((ushort8*)(isZ ? zl : cl))[(size_t)lr * 64 + lane] = l8;

#pragma unroll
    for (int off = 32; off >= 1; off >>= 1) s += __shfl_xor(s, off, 64);
    if (lane == 0) {
        if (isZ) x2[lr] = s;
        else     hne2[lr] = -0.5f * s;
    }
}

// ---------------------------------------------------------------------------
// Kernel 2: bf16 MFMA GEMM + fused top-2 argmax of g = x.e - e2/2.
// (round-4 version verbatim)
// ---------------------------------------------------------------------------
__global__ __launch_bounds__(256, 2) void vq_gemm(
    const unsigned short* __restrict__ zh, const unsigned short* __restrict__ ch,
    const float* __restrict__ hne2,
    float* __restrict__ pG, int* __restrict__ pN, float* __restrict__ pG2) {
    __shared__ short8 AsC[1024];   // 128 rows x 8 octet-cells, XOR-swizzled (16 KB)
    __shared__ short8 BsC[2048];   // 256 codes x 8 octet-cells, XOR-swizzled (32 KB)

    const int tid  = threadIdx.x;
    const int w    = tid >> 6;
    const int lane = tid & 63;
    const int wM   = w & 1;
    const int wN   = w >> 1;
    const int rowBase   = blockIdx.x * 128;
    const int half      = blockIdx.y;
    const int codeBase0 = half * 4096;

    const int low3 = lane & 7, m15 = lane & 15, hi4 = lane >> 4;

    unsigned aOff[4];
#pragma unroll
    for (int i = 0; i < 4; ++i) {
        int cell = (w * 4 + i) * 64 + lane;
        int r = cell >> 3, qs = cell & 7, q = qs ^ (r & 7);
        aOff[i] = ((unsigned)(rowBase + r) * DIM + q * 8) * 2;
    }
    unsigned bOff[8];
#pragma unroll
    for (int i = 0; i < 8; ++i) {
        int cell = (w * 8 + i) * 64 + lane;
        int c = cell >> 3, qs = cell & 7, q = qs ^ (c & 7);
        bOff[i] = ((unsigned)c * DIM + q * 8) * 2;   // relative to code-tile base
    }

    int rIdx[4], cIdx[8];
#pragma unroll
    for (int mf = 0; mf < 4; ++mf) rIdx[mf] = (wM * 64 + mf * 16 + m15) * 8;
#pragma unroll
    for (int nf = 0; nf < 8; ++nf) cIdx[nf] = (wN * 128 + nf * 16 + m15) * 8;

    float g1[4][4], g2[4][4];
    int   n1[4][4];
#pragma unroll
    for (int mf = 0; mf < 4; ++mf)
#pragma unroll
        for (int rg = 0; rg < 4; ++rg) {
            g1[mf][rg] = -3.4e38f; g2[mf][rg] = -3.4e38f; n1[mf][rg] = 0;
        }

    const char* pA = (const char*)zh;
    for (int ct = 0; ct < 16; ++ct) {
        const int codeBase = codeBase0 + ct * 256;
        const char* pB = (const char*)ch + (size_t)codeBase * (DIM * 2);
        float4x acc[4][8];
#pragma unroll
        for (int mf = 0; mf < 4; ++mf)
#pragma unroll
            for (int nf = 0; nf < 8; ++nf) acc[mf][nf] = (float4x){0.f, 0.f, 0.f, 0.f};

        for (int dc = 0; dc < DIM; dc += 64) {
            const int dc2 = dc * 2;
            __syncthreads();
#pragma unroll
            for (int i = 0; i < 4; ++i)
                gl_lds16(pA + aOff[i] + dc2, &AsC[(w * 4 + i) * 64]);
#pragma unroll
            for (int i = 0; i < 8; ++i)
                gl_lds16(pB + bOff[i] + dc2, &BsC[(w * 8 + i) * 64]);
            __syncthreads();

#pragma unroll
            for (int ks = 0; ks < 2; ++ks) {
                const int qx = (ks * 4 + hi4) ^ low3;
                short8 a[4];
#pragma unroll
                for (int mf = 0; mf < 4; ++mf) a[mf] = AsC[rIdx[mf] + qx];
#pragma unroll
                for (int nf = 0; nf < 8; ++nf) {
                    short8 b = BsC[cIdx[nf] + qx];
#pragma unroll
                    for (int mf = 0; mf < 4; ++mf)
                        acc[mf][nf] = __builtin_amdgcn_mfma_f32_16x16x32_bf16(
                            a[mf], b, acc[mf][nf], 0, 0, 0);
                }
            }
        }

        // epilogue: running top-2 of g (ties -> g2=g1 -> gap 0 -> rescued)
#pragma unroll
        for (int nf = 0; nf < 8; ++nf) {
            int nb = codeBase + wN * 128 + nf * 16 + m15;
            float hv = hne2[nb];
#pragma unroll
            for (int mf = 0; mf < 4; ++mf) {
#pragma unroll
                for (int rg = 0; rg < 4; ++rg) {
                    float g = acc[mf][nf][rg] + hv;
                    if (g > g1[mf][rg]) {
                        g2[mf][rg] = g1[mf][rg];
                        g1[mf][rg] = g; n1[mf][rg] = nb;
                    } else {
                        g2[mf][rg] = fmaxf(g2[mf][rg], g);
                    }
                }
            }
        }
    }

    // cross-lane top-2 merge over the 16 lanes sharing each row
#pragma unroll
    for (int mf = 0; mf < 4; ++mf)
#pragma unroll
        for (int rg = 0; rg < 4; ++rg) {
            float a1 = g1[mf][rg], a2 = g2[mf][rg];
            int   an = n1[mf][rg];
#pragma unroll
            for (int off = 1; off <= 8; off <<= 1) {
                float b1 = __shfl_xor(a1, off, 64);
                int   bn = __shfl_xor(an, off, 64);
                float b2 = __shfl_xor(a2, off, 64);
                if (b1 > a1 || (b1 == a1 && bn < an)) {
                    a2 = fmaxf(a1, b2); a1 = b1; an = bn;
                } else {
                    a2 = fmaxf(a2, b1);
                }
            }
            if (m15 == 0) {
                int row  = rowBase + wM * 64 + mf * 16 + hi4 * 4 + rg;
                int slot = half * 2 + wN;          // unique per (block.y, wave-col)
                pG [slot * N_VEC + row] = a1;
                pN [slot * N_VEC + row] = an;
                pG2[slot * N_VEC + row] = a2;
            }
        }
}

// ---------------------------------------------------------------------------
// Kernel 3: merge 4 partial slots per row, flag near-ties, compact flagged
// rows into rescueRows (cap MAXC; overflow escalates directly to exact).
// ---------------------------------------------------------------------------
__global__ __launch_bounds__(256) void vq_scan(
    float* __restrict__ pG, const int* __restrict__ pN,
    const float* __restrict__ pG2,
    int* __restrict__ provIdx, int* __restrict__ flags,
    unsigned long long* __restrict__ keys,
    int* __restrict__ rescueRows, int* __restrict__ rescueCnt,
    int* __restrict__ rescueRows2, int* __restrict__ rescueCnt2) {
    int r = blockIdx.x * 256 + threadIdx.x;
    float g1 = pG[r], g2 = pG2[r];
    int   n1 = pN[r];
#pragma unroll
    for (int s = 1; s < 4; ++s) {
        float a1 = pG [s * N_VEC + r];
        int   an = pN [s * N_VEC + r];
        float a2 = pG2[s * N_VEC + r];
        if (a1 > g1 || (a1 == g1 && an < n1)) {
            g2 = fmaxf(g1, a2); g1 = a1; n1 = an;
        } else {
            g2 = fmaxf(g2, a1);
        }
    }
    provIdx[r] = n1;
    pG[r] = g1;                       // merged best (for loss)
    int fl = (g1 - g2 < MARGIN) ? 1 : 0;
    flags[r] = fl;
    if (fl) {
        keys[r] = ~0ull;
        int p = atomicAdd(rescueCnt, 1);
        if (p < MAXC) {
            rescueRows[p] = r;
        } else {                      // never in practice; correctness fallback
            int q = atomicAdd(rescueCnt2, 1);
            rescueRows2[q] = r;
        }
    }
}

// ---------------------------------------------------------------------------
// Kernel 4: MID rescue — split-bf16 MFMA over compacted flagged rows, using
// the main gemm's proven geometry. Block = 128 compact rows x 256-code strip
// (strip = blockIdx.y of 32); persistent row-tile loop, stride gridDim.x=16.
// 3 passes: xh.eh + xl.eh + xh.el (fp32 accum); residual ~3e-4 sigma.
// Per-row top-2 over the strip -> 64 partial slots (blockIdx.y*2 + wN).
// rescueRows zero-padded: slots >= cnt harmlessly compute row 0.
// ---------------------------------------------------------------------------
__global__ __launch_bounds__(256, 2) void vq_mid(
    const unsigned short* __restrict__ zh, const unsigned short* __restrict__ zl,
    const unsigned short* __restrict__ ch, const unsigned short* __restrict__ cl,
    const float* __restrict__ hne2,
    const int* __restrict__ rescueRows, const int* __restrict__ rescueCnt,
    float* __restrict__ pGm, int* __restrict__ pNm, float* __restrict__ pG2m) {
    __shared__ short8 AsC[1024];   // 128 rows x 8 octet-cells, XOR-swizzled (16 KB)
    __shared__ short8 BsC[2048];   // 256 codes x 8 octet-cells (32 KB)
    __shared__ int rowOf[128];

    const int tid  = threadIdx.x;
    const int w    = tid >> 6;
    const int lane = tid & 63;
    const int wM   = w & 1;
    const int wN   = w >> 1;
    int cnt = *rescueCnt; if (cnt > MAXC) cnt = MAXC;
    const int rowTiles = (cnt + 127) >> 7;
    const int codeBase = blockIdx.y * 256;

    const int low3 = lane & 7, m15 = lane & 15, hi4 = lane >> 4;

    int aCellR[4], aCellQ[4];
#pragma unroll
    for (int i = 0; i < 4; ++i) {
        int cell = (w * 4 + i) * 64 + lane;
        aCellR[i] = cell >> 3;
        aCellQ[i] = (cell & 7) ^ (aCellR[i] & 7);
    }
    unsigned bOff[8];
#pragma unroll
    for (int i = 0; i < 8; ++i) {
        int cell = (w * 8 + i) * 64 + lane;
        int c = cell >> 3, qs = cell & 7, q = qs ^ (c & 7);
        bOff[i] = ((unsigned)(codeBase + c) * DIM + q * 8) * 2;
    }

    int rIdx[4], cIdx[8];
#pragma unroll
    for (int mf = 0; mf < 4; ++mf) rIdx[mf] = (wM * 64 + mf * 16 + m15) * 8;
#pragma unroll
    for (int nf = 0; nf < 8; ++nf) cIdx[nf] = (wN * 128 + nf * 16 + m15) * 8;

    for (int rt = blockIdx.x; rt < rowTiles; rt += gridDim.x) {
        __syncthreads();   // prior iteration's LDS/rowOf use fully done
        if (tid < 128) rowOf[tid] = rescueRows[rt * 128 + tid];
        __syncthreads();

        unsigned aOff[4];
#pragma unroll
        for (int i = 0; i < 4; ++i)
            aOff[i] = ((unsigned)rowOf[aCellR[i]] * DIM + aCellQ[i] * 8) * 2;

        float4x acc[4][8];
#pragma unroll
        for (int mf = 0; mf < 4; ++mf)
#pragma unroll
            for (int nf = 0; nf < 8; ++nf) acc[mf][nf] = (float4x){0.f, 0.f, 0.f, 0.f};

#pragma unroll
        for (int pass = 0; pass < 3; ++pass) {
            const char* pA = (const char*)(pass == 1 ? zl : zh);
            const char* pB = (const char*)(pass == 2 ? cl : ch);
            for (int dc = 0; dc < DIM; dc += 64) {
                const int dc2 = dc * 2;
                __syncthreads();
#pragma unroll
                for (int i = 0; i < 4; ++i)
                    gl_lds16(pA + aOff[i] + dc2, &AsC[(w * 4 + i) * 64]);
#pragma unroll
                for (int i = 0; i < 8; ++i)
                    gl_lds16(pB + bOff[i] + dc2, &BsC[(w * 8 + i) * 64]);
                __syncthreads();

#pragma unroll
                for (int ks = 0; ks < 2; ++ks) {
                    const int qx = (ks * 4 + hi4) ^ low3;
                    short8 a[4];
#pragma unroll
                    for (int mf = 0; mf < 4; ++mf) a[mf] = AsC[rIdx[mf] + qx];
#pragma unroll
                    for (int nf = 0; nf < 8; ++nf) {
                        short8 b = BsC[cIdx[nf] + qx];
#pragma unroll
                        for (int mf = 0; mf < 4; ++mf)
                            acc[mf][nf] = __builtin_amdgcn_mfma_f32_16x16x32_bf16(
                                a[mf], b, acc[mf][nf], 0, 0, 0);
                    }
                }
            }
        }

        // top-2 epilogue over the 256-code strip
        float g1[4][4], g2[4][4];
        int   n1[4][4];
#pragma unroll
        for (int mf = 0; mf < 4; ++mf)
#pragma unroll
            for (int rg = 0; rg < 4; ++rg) {
                g1[mf][rg] = -3.4e38f; g2[mf][rg] = -3.4e38f; n1[mf][rg] = 0;
            }
#pragma unroll
        for (int nf = 0; nf < 8; ++nf) {
            int nb = codeBase + wN * 128 + nf * 16 + m15;
            float hv = hne2[nb];
#pragma unroll
            for (int mf = 0; mf < 4; ++mf) {
#pragma unroll
                for (int rg = 0; rg < 4; ++rg) {
                    float g = acc[mf][nf][rg] + hv;
                    if (g > g1[mf][rg]) {
                        g2[mf][rg] = g1[mf][rg];
                        g1[mf][rg] = g; n1[mf][rg] = nb;
                    } else {
                        g2[mf][rg] = fmaxf(g2[mf][rg], g);
                    }
                }
            }
        }
#pragma unroll
        for (int mf = 0; mf < 4; ++mf)
#pragma unroll
            for (int rg = 0; rg < 4; ++rg) {
                float a1 = g1[mf][rg], a2 = g2[mf][rg];
                int   an = n1[mf][rg];
#pragma unroll
                for (int off = 1; off <= 8; off <<= 1) {
                    float b1 = __shfl_xor(a1, off, 64);
                    int   bn = __shfl_xor(an, off, 64);
                    float b2 = __shfl_xor(a2, off, 64);
                    if (b1 > a1 || (b1 == a1 && bn < an)) {
                        a2 = fmaxf(a1, b2); a1 = b1; an = bn;
                    } else {
                        a2 = fmaxf(a2, b1);
                    }
                }
                if (m15 == 0) {
                    int sPos = rt * 128 + wM * 64 + mf * 16 + hi4 * 4 + rg;
                    int slot = blockIdx.y * 2 + wN;
                    pGm [slot * MAXC + sPos] = a1;
                    pNm [slot * MAXC + sPos] = an;
                    pG2m[slot * MAXC + sPos] = a2;
                }
            }
    }
}

// ---------------------------------------------------------------------------
// Kernel 5: merge 64 mid slots per compact row; escalate gap<MARGIN2 rows to
// exact rescue, else write final key (kv = -g packed with code).
// ---------------------------------------------------------------------------
__global__ __launch_bounds__(256) void vq_scan2(
    const float* __restrict__ pGm, const int* __restrict__ pNm,
    const float* __restrict__ pG2m,
    const int* __restrict__ rescueRows, const int* __restrict__ rescueCnt,
    unsigned long long* __restrict__ keys,
    int* __restrict__ rescueRows2, int* __restrict__ rescueCnt2) {
    int s = blockIdx.x * 256 + threadIdx.x;
    int cnt = *rescueCnt; if (cnt > MAXC) cnt = MAXC;
    if (s >= cnt) return;
    float g1 = pGm[s], g2 = pG2m[s];
    int   n1 = pNm[s];
#pragma unroll 8
    for (int k = 1; k < 64; ++k) {
        float a1 = pGm [k * MAXC + s];
        int   an = pNm [k * MAXC + s];
        float a2 = pG2m[k * MAXC + s];
        if (a1 > g1 || (a1 == g1 && an < n1)) {
            g2 = fmaxf(g1, a2); g1 = a1; n1 = an;
        } else {
            g2 = fmaxf(g2, a1);
        }
    }
    int row = rescueRows[s];
    if (g1 - g2 < MARGIN2) {
        keys[row] = ~0ull;
        int p = atomicAdd(rescueCnt2, 1);
        rescueRows2[p] = row;
    } else {
        keys[row] = ((unsigned long long)__float_as_uint(-g1) << 32) |
                    (unsigned long long)(unsigned)n1;
    }
}

// ---------------------------------------------------------------------------
// Kernel 6: exact fp32 rescue over escalated rows (expected cnt2 ~ tens).
// 64 slots x 512 codes per block, persistent over row-tiles.
// ---------------------------------------------------------------------------
#define RBM 64
#define RBK 256
#define RBD 32

__global__ __launch_bounds__(256, 2) void vq_exact(
    const float* __restrict__ z, const float* __restrict__ cb,
    const float* __restrict__ hne2,
    const int* __restrict__ rescueRows2, const int* __restrict__ rescueCnt2,
    unsigned long long* __restrict__ keys) {
    __shared__ float As[RBD][RBM];   // 8 KB, transposed
    __shared__ float Bs[RBD][RBK];   // 32 KB, transposed
    __shared__ int   rowOf[RBM];

    const int tid = threadIdx.x;
    const int tx  = tid & 31;
    const int ty  = tid >> 5;
    const int cnt = *rescueCnt2;
    const int codeBase0 = blockIdx.y * 512;      // grid.y = 16
    const int sw = (tx & 8) ? 4 : 0;
    const int sRow = tid >> 2;
    const int sQ   = tid & 3;

    for (int rt = blockIdx.x; rt * RBM < cnt; rt += gridDim.x) {
        const int slotBase = rt * RBM;
        __syncthreads();
        if (tid < RBM) rowOf[tid] = rescueRows2[slotBase + tid];
        __syncthreads();

        float best[8];
        int   bidx[8];
#pragma unroll
        for (int i = 0; i < 8; ++i) { best[i] = 3.4e38f; bidx[i] = K_CODES; }

        for (int kt = 0; kt < 2; ++kt) {
            const int codeBase = codeBase0 + kt * RBK;
            float acc[8][8];
#pragma unroll
            for (int i = 0; i < 8; ++i)
#pragma unroll
                for (int j = 0; j < 8; ++j) acc[i][j] = 0.0f;

            for (int dc = 0; dc < DIM; dc += RBD) {
                __syncthreads();
                {
                    const float* srcA = z + (size_t)rowOf[sRow] * DIM + dc + sQ * 8;
                    float4 va0 = ((const float4*)srcA)[0];
                    float4 va1 = ((const float4*)srcA)[1];
                    int c0 = sQ * 8;
                    As[c0 + 0][sRow] = va0.x; As[c0 + 1][sRow] = va0.y;
                    As[c0 + 2][sRow] = va0.z; As[c0 + 3][sRow] = va0.w;
                    As[c0 + 4][sRow] = va1.x; As[c0 + 5][sRow] = va1.y;
                    As[c0 + 6][sRow] = va1.z; As[c0 + 7][sRow] = va1.w;
                }
                {
                    const float4* srcB = (const float4*)(cb + (size_t)(codeBase + tid) * DIM + dc);
#pragma unroll
                    for (int j = 0; j < 8; ++j) {
                        float4 v = srcB[j];
                        Bs[j * 4 + 0][tid] = v.x; Bs[j * 4 + 1][tid] = v.y;
                        Bs[j * 4 + 2][tid] = v.z; Bs[j * 4 + 3][tid] = v.w;
                    }
                }
                __syncthreads();

#pragma unroll
                for (int d = 0; d < RBD; ++d) {
                    float a[8], b[8];
                    *(float4*)&a[0] = *(const float4*)&As[d][ty * 8];
                    *(float4*)&a[4] = *(const float4*)&As[d][ty * 8 + 4];
                    *(float4*)&b[0] = *(const float4*)&Bs[d][tx * 8 + sw];
                    *(float4*)&b[4] = *(const float4*)&Bs[d][tx * 8 + (sw ^ 4)];
#pragma unroll
                    for (int i = 0; i < 8; ++i)
#pragma unroll
                        for (int j = 0; j < 8; ++j) acc[i][j] += a[i] * b[j];
                }
            }

#pragma unroll
            for (int j = 0; j < 8; ++j) {
                int code = codeBase + tx * 8 + ((j < 4) ? (sw + j) : ((sw ^ 4) + j - 4));
                float ev = -hne2[code];           // = e2/2
#pragma unroll
                for (int i = 0; i < 8; ++i) {
                    float kv = ev - acc[i][j];    // = e2/2 - x.e  (> 0)
                    if (kv < best[i] || (kv == best[i] && code < bidx[i])) {
                        best[i] = kv;
                        bidx[i] = code;
                    }
                }
            }
        }

#pragma unroll
        for (int off = 16; off >= 1; off >>= 1) {
#pragma unroll
            for (int i = 0; i < 8; ++i) {
                float od = __shfl_xor(best[i], off, 64);
                int   oi = __shfl_xor(bidx[i], off, 64);
                if (od < best[i] || (od == best[i] && oi < bidx[i])) {
                    best[i] = od;
                    bidx[i] = oi;
                }
            }
        }

        if (tx == 0) {
#pragma unroll
            for (int i = 0; i < 8; ++i) {
                int slot = slotBase + ty * 8 + i;
                if (slot < cnt) {
                    unsigned long long key =
                        ((unsigned long long)__float_as_uint(best[i]) << 32) |
                        (unsigned long long)(unsigned)bidx[i];
                    atomicMin(&keys[rowOf[ty * 8 + i]], key);
                }
            }
        }
    }
}

// ---------------------------------------------------------------------------
// Kernel 7: final per-row results: index, counts, loss partial, z_q gather.
// ---------------------------------------------------------------------------
__global__ __launch_bounds__(256) void vq_final(
    const float* __restrict__ gBest, const int* __restrict__ provIdx,
    const int* __restrict__ flags, const unsigned long long* __restrict__ keys,
    const float* __restrict__ x2, const float* __restrict__ cb,
    float* __restrict__ zq, float* __restrict__ idxf,
    float* __restrict__ counts, float* __restrict__ lossAcc) {
    __shared__ int   sIdx[256];
    __shared__ float wsum[4];
    const int tid = threadIdx.x;
    const int r   = blockIdx.x * 256 + tid;

    int n; float dist;
    if (flags[r]) {
        unsigned long long k = keys[r];
        n = (int)(unsigned)(k & 0xffffffffu);
        float kv = __uint_as_float((unsigned)(k >> 32));
        dist = x2[r] + 2.0f * kv;          // x2 + e2 - 2 x.e
    } else {
        n = provIdx[r];
        dist = x2[r] - 2.0f * gBest[r];
    }
    sIdx[tid] = n;
    idxf[r]   = (float)n;
    atomicAdd(&counts[n], 1.0f);

    float ls = dist;
#pragma unroll
    for (int off = 32; off >= 1; off >>= 1) ls += __shfl_xor(ls, off, 64);
    if ((tid & 63) == 0) wsum[tid >> 6] = ls;
    __syncthreads();
    if (tid == 0) atomicAdd(lossAcc, wsum[0] + wsum[1] + wsum[2] + wsum[3]);

    const float4* cb4 = (const float4*)cb;
    float4* zq4 = (float4*)(zq + (size_t)blockIdx.x * 256 * DIM);
    for (int t = tid; t < 256 * (DIM / 4); t += 256) {
        int row = t >> 7, f4 = t & 127;
        zq4[(size_t)row * 128 + f4] = cb4[(size_t)sIdx[row] * 128 + f4];
    }
}

// ---------------------------------------------------------------------------
// Kernel 8: finalize scalars
// ---------------------------------------------------------------------------
__global__ __launch_bounds__(256) void vq_finalize(const float* __restrict__ counts,
                                                   const float* __restrict__ lossAcc,
                                                   float* __restrict__ out_loss,
                                                   float* __restrict__ out_perp) {
    __shared__ float wsum[4];
    int tid = threadIdx.x;
    float s = 0.0f;
    for (int i = tid; i < K_CODES; i += 256) {
        float p = counts[i] * (1.0f / (float)N_VEC);
        s += p * logf(p + 1e-10f);
    }
#pragma unroll
    for (int off = 32; off >= 1; off >>= 1) s += __shfl_xor(s, off, 64);
    if ((tid & 63) == 0) wsum[tid >> 6] = s;
    __syncthreads();
    if (tid == 0) {
        *out_perp = expf(-(wsum[0] + wsum[1] + wsum[2] + wsum[3]));
        *out_loss = 1.25f * lossAcc[0] / (float)(N_VEC * DIM);
    }
}

// ---------------------------------------------------------------------------
// ws layout (bytes), total ~93 MB (identical footprint to round 6):
//   x2 @0 131072 | hne2 @131072 32768 | counts @163840 32768
//   lossAcc @196608 4 | rescueCnt @196612 4 | rescueCnt2 @196616 4
//   provIdx @262144 131072 | flags @393216 131072 | keys @524288 262144
//   rescueRows @786432 131072 | rescueRows2 @917504 131072
//   pG @1048576 524288 | pN @1572864 524288 | pG2 @2097152 524288
//   pGm @2621440 2097152 | pNm @4718592 2097152 | pG2m @6815744 2097152
//   zh @8912896 33554432 | zl @42467328 33554432
//   ch @76021760 8388608 | cl @84410368 8388608  -> end 92798976
// ---------------------------------------------------------------------------
extern "C" void kernel_launch(void* const* d_in, const int* in_sizes, int n_in,
                              void* d_out, int out_size, void* d_ws, size_t ws_size,
                              hipStream_t stream) {
    (void)in_sizes; (void)n_in; (void)out_size; (void)ws_size;
    const float* z  = (const float*)d_in[0];
    const float* cb = (const float*)d_in[1];

    char* ws = (char*)d_ws;
    float* x2         = (float*)(ws + 0);
    float* hne2       = (float*)(ws + 131072);
    float* counts     = (float*)(ws + 163840);
    float* lossAcc    = (float*)(ws + 196608);
    int*   rescueCnt  = (int*)  (ws + 196612);
    int*   rescueCnt2 = (int*)  (ws + 196616);
    int*   provIdx    = (int*)  (ws + 262144);
    int*   flags      = (int*)  (ws + 393216);
    unsigned long long* keys = (unsigned long long*)(ws + 524288);
    int*   rescueRows  = (int*)(ws + 786432);
    int*   rescueRows2 = (int*)(ws + 917504);
    float* pG         = (float*)(ws + 1048576);
    int*   pN         = (int*)  (ws + 1572864);
    float* pG2        = (float*)(ws + 2097152);
    float* pGm        = (float*)(ws + 2621440);
    int*   pNm        = (int*)  (ws + 4718592);
    float* pG2m       = (float*)(ws + 6815744);
    unsigned short* zh = (unsigned short*)(ws + 8912896);
    unsigned short* zl = (unsigned short*)(ws + 42467328);
    unsigned short* ch = (unsigned short*)(ws + 76021760);
    unsigned short* cl = (unsigned short*)(ws + 84410368);

    float* out      = (float*)d_out;
    float* zq       = out;
    float* out_loss = out + 16777216;
    float* idxf     = out + 16777217;
    float* out_perp = out + 16777217 + 32768;

    // zero counts + lossAcc + rescueCnt + rescueCnt2 (contiguous), and the
    // two rescue-row lists (zero-padding for the indirected tiles)
    hipMemsetAsync(counts, 0, 32768 + 12, stream);
    hipMemsetAsync(rescueRows, 0, 262144, stream);
    vq_prep<<<(N_VEC + K_CODES) / 4, 256, 0, stream>>>(z, cb, x2, hne2, zh, zl, ch, cl);
    dim3 grid(N_VEC / 128, 2);
    vq_gemm<<<grid, 256, 0, stream>>>(zh, ch, hne2, pG, pN, pG2);
    vq_scan<<<N_VEC / 256, 256, 0, stream>>>(pG, pN, pG2, provIdx, flags, keys,
                                             rescueRows, rescueCnt,
                                             rescueRows2, rescueCnt2);
    dim3 mgrid(16, 32);
    vq_mid<<<mgrid, 256, 0, stream>>>(zh, zl, ch, cl, hne2, rescueRows, rescueCnt,
                                      pGm, pNm, pG2m);
    vq_scan2<<<MAXC / 256, 256, 0, stream>>>(pGm, pNm, pG2m, rescueRows, rescueCnt,
                                             keys, rescueRows2, rescueCnt2);
    dim3 egrid(8, 16);
    vq_exact<<<egrid, 256, 0, stream>>>(z, cb, hne2, rescueRows2, rescueCnt2, keys);
    vq_final<<<N_VEC / 256, 256, 0, stream>>>(pG, provIdx, flags, keys, x2, cb,
                                              zq, idxf, counts, lossAcc);
    vq_finalize<<<1, 256, 0, stream>>>(counts, lossAcc, out_loss, out_perp);
}